// Round 18
// baseline (236.615 us; speedup 1.0000x reference)
//
#include <hip/hip_runtime.h>
#include <math.h>

#define TS 256
#define BB 1024
#define NQ 8
#define INDIM 128
#define CATDIM 136
#define INV2PI 0.15915494309189535f
#define LOG2E  1.4426950408889634f

typedef float v2f __attribute__((ext_vector_type(2)));
typedef __fp16 v2h __attribute__((ext_vector_type(2)));

__device__ __forceinline__ float dpp_xor1(float v) {
    return __int_as_float(__builtin_amdgcn_mov_dpp(__float_as_int(v), 0xB1, 0xF, 0xF, true));
}
__device__ __forceinline__ float dpp_xor2(float v) {
    return __int_as_float(__builtin_amdgcn_mov_dpp(__float_as_int(v), 0x4E, 0xF, 0xF, true));
}
__device__ __forceinline__ float dpp_xor8(float v) {   // row_ror:8 within 16-lane row = lane^8
    return __int_as_float(__builtin_amdgcn_mov_dpp(__float_as_int(v), 0x128, 0xF, 0xF, true));
}
__device__ __forceinline__ float swz4(float v)  {      // ds_swizzle xor 4
    return __int_as_float(__builtin_amdgcn_ds_swizzle(__float_as_int(v), 0x101F));
}
__device__ __forceinline__ float swz16(float v) {      // ds_swizzle xor 16
    return __int_as_float(__builtin_amdgcn_ds_swizzle(__float_as_int(v), 0x401F));
}
__device__ __forceinline__ float swz20(float v) {      // ds_swizzle xor 20
    return __int_as_float(__builtin_amdgcn_ds_swizzle(__float_as_int(v), 0x501F));
}
__device__ __forceinline__ float hw_sin(float x) { float r; asm("v_sin_f32 %0, %1" : "=v"(r) : "v"(x)); return r; }
__device__ __forceinline__ float hw_cos(float x) { float r; asm("v_cos_f32 %0, %1" : "=v"(r) : "v"(x)); return r; }
__device__ __forceinline__ float hw_exp(float x) { float r; asm("v_exp_f32 %0, %1" : "=v"(r) : "v"(x)); return r; }
__device__ __forceinline__ float hw_rcp(float x) { float r; asm("v_rcp_f32 %0, %1" : "=v"(r) : "v"(x)); return r; }
__device__ __forceinline__ v2f mk2(float x, float y) { v2f r; r.x = x; r.y = y; return r; }
__device__ __forceinline__ v2f pk_fma(v2f a, v2f b, v2f c) {
    v2f d; asm("v_pk_fma_f32 %0, %1, %2, %3" : "=v"(d) : "v"(a), "v"(b), "v"(c)); return d;
}
// f16 pair dot with f32 accumulate: d = a.x*b.x + a.y*b.y + c
__device__ __forceinline__ float fdot2(v2h a, v2h b, float c) {
    float d; asm("v_dot2_f32_f16 %0, %1, %2, %3" : "=v"(d) : "v"(a), "v"(b), "v"(c)); return d;
}

// ============ Single fused kernel: x-proj + TM recurrence ============
// R17b: ONE element per 64-lane wave (1024 waves -> all 1024 SIMDs covered).
// lane = k1*32 + g1*16 + l3*8 + g0*4 + l1*2 + l0 ; q = 4*l0+2*l1+l3 ;
// g = g0+2*g1 ; x-chunk = 8 columns at 8*(8*k1+q). x-weights in f16
// (v_dot2_f32_f16, f32 accum) so the whole working set fits ~128 VGPRs
// (kills the per-step weight reloads diagnosed R16). Reduce = verified R14
// 3-stage DPP butterfly + one shfl_xor(32) stage. All else verbatim R15/R16:
// sorted DPP allgather, transfer chain, sel-fma own-E, activation, 3-swizzle
// gate gather, lane-local LSTM, DPP h-butterfly.
__launch_bounds__(64, 1)
__attribute__((amdgpu_waves_per_eu(1, 1)))
__global__ void qlstm_f(const float* __restrict__ x,
    const float* __restrict__ Wf, const float* __restrict__ bf, const float* __restrict__ Pf,
    const float* __restrict__ Wi, const float* __restrict__ bi, const float* __restrict__ Pi,
    const float* __restrict__ Wg, const float* __restrict__ bg, const float* __restrict__ Pg,
    const float* __restrict__ Wo, const float* __restrict__ bo, const float* __restrict__ Po,
    float* __restrict__ out, float* __restrict__ hst, float* __restrict__ cst)
{
    const int lane = threadIdx.x;
    const int l0 = lane & 1, l1 = (lane >> 1) & 1, l3 = (lane >> 3) & 1;
    const int q = 4 * l0 + 2 * l1 + l3;
    const int g = ((lane >> 2) & 1) | ((lane >> 3) & 2);
    const int k1 = lane >> 5;
    const int b = blockIdx.x;
    const int c = 8 * k1 + q;                 // 8-column chunk id

    const float* W; const float* P; const float* bs;
    if (g == 0)      { W = Wf; P = Pf; bs = bf; }
    else if (g == 1) { W = Wi; P = Pi; bs = bi; }
    else if (g == 2) { W = Wg; P = Pg; bs = bg; }
    else             { W = Wo; P = Po; bs = bo; }

    // ---- per-wire trig constants ----
    float Chw[8], nSw[8], hsp0[8], cp0c[8];
    #pragma unroll
    for (int w = 0; w < 8; ++w) {
        float s1, c1, s0, c0;
        __sincosf(P[8 + w], &s1, &c1);
        __sincosf(P[w], &s0, &c0);
        Chw[w] = 0.5f * c1;
        nSw[w] = -s1;
        hsp0[w] = 0.5f * s0;
        cp0c[w] = c0;
    }

    // ---- x-weights: 8 rows x own 8-wide chunk, 1/2π-scaled, f16-packed ----
    v2h xw[8][4];
    #pragma unroll
    for (int j = 0; j < 8; ++j) {
        const float* Wj = W + j * CATDIM + 8 * c;
        #pragma unroll
        for (int p2 = 0; p2 < 4; ++p2)
            xw[j][p2] = __builtin_amdgcn_cvt_pkrtz(INV2PI * Wj[2*p2], INV2PI * Wj[2*p2+1]);
    }

    // ---- own-row h-weights (f32), h-butterfly slot order folded ----
    v2f whq[4];
    {
        const float* Wq = W + q * CATDIM + INDIM;
        #pragma unroll
        for (int p2 = 0; p2 < 4; ++p2)
            whq[p2] = mk2(INV2PI * Wq[q ^ (2 * p2)], INV2PI * Wq[q ^ (2 * p2 + 1)]);
    }
    const float bq = INV2PI * bs[q];

    // ---- activation constants; kk*log2e folded into E-select ----
    const float kl = ((g == 2) ? 2.f : -1.f) * LOG2E;
    const float Aa = (g == 2) ? 1.f : 0.f;
    const float Bb = (g == 2) ? -1.f : 1.f;
    float sel[8];
    #pragma unroll
    for (int i = 0; i < 8; ++i) sel[i] = (q == i) ? kl : 0.f;

    // ---- state ----
    float s0h = 0.f, s1h = 0.f, s2h = 0.f, s3h = 0.f;
    float s4h = 0.f, s5h = 0.f, s6h = 0.f, s7h = 0.f;
    float c_own = 0.f, hv = 0.f;

    // ---- x chunk (8 floats) preload t=0, converted to 4 f16-pairs ----
    const float* xptr = x + (size_t)b * INDIM + 8 * c;
    v2h xh[4];
    {
        float4 a0 = *(const float4*)(xptr);
        float4 a1 = *(const float4*)(xptr + 4);
        xh[0] = __builtin_amdgcn_cvt_pkrtz(a0.x, a0.y);
        xh[1] = __builtin_amdgcn_cvt_pkrtz(a0.z, a0.w);
        xh[2] = __builtin_amdgcn_cvt_pkrtz(a1.x, a1.y);
        xh[3] = __builtin_amdgcn_cvt_pkrtz(a1.z, a1.w);
    }
    xptr += (size_t)BB * INDIM;

    const bool emit = (lane & 0x34) == 0;
    float* optr = out + (size_t)b * NQ + q;

    for (int t = 0; t < TS; ++t) {
        // ---- 8 partial x-dots over own 8-chunk (f16 dot2, f32 accum) ----
        float pt[8];
        #pragma unroll
        for (int j = 0; j < 8; ++j) {
            float acc = fdot2(xh[0], xw[j][0], 0.f);
            acc = fdot2(xh[1], xw[j][1], acc);
            acc = fdot2(xh[2], xw[j][2], acc);
            acc = fdot2(xh[3], xw[j][3], acc);
            pt[j] = acc;
        }

        // prefetch next x chunk, convert immediately (f32 regs transient)
        {
            float4 a0 = *(const float4*)(xptr);
            float4 a1 = *(const float4*)(xptr + 4);
            xptr += (t < TS - 2) ? (size_t)BB * INDIM : 0;
            xh[0] = __builtin_amdgcn_cvt_pkrtz(a0.x, a0.y);
            xh[1] = __builtin_amdgcn_cvt_pkrtz(a0.z, a0.w);
            xh[2] = __builtin_amdgcn_cvt_pkrtz(a1.x, a1.y);
            xh[3] = __builtin_amdgcn_cvt_pkrtz(a1.z, a1.w);
        }

        // ---- butterfly reduce (masks 1,2,8 — verified R14) + xor32 stage ----
        {
            float s, r;
            s = l0 ? pt[0] : pt[4]; r = dpp_xor1(s); pt[0] = (l0 ? pt[4] : pt[0]) + r;
            s = l0 ? pt[1] : pt[5]; r = dpp_xor1(s); pt[1] = (l0 ? pt[5] : pt[1]) + r;
            s = l0 ? pt[2] : pt[6]; r = dpp_xor1(s); pt[2] = (l0 ? pt[6] : pt[2]) + r;
            s = l0 ? pt[3] : pt[7]; r = dpp_xor1(s); pt[3] = (l0 ? pt[7] : pt[3]) + r;
            s = l1 ? pt[0] : pt[2]; r = dpp_xor2(s); pt[0] = (l1 ? pt[2] : pt[0]) + r;
            s = l1 ? pt[1] : pt[3]; r = dpp_xor2(s); pt[1] = (l1 ? pt[3] : pt[1]) + r;
            s = l3 ? pt[0] : pt[1]; r = dpp_xor8(s); pt[0] = (l3 ? pt[1] : pt[0]) + r;
            pt[0] += __shfl_xor(pt[0], 32, 64);   // sum the two 64-col halves
        }

        // ---- own-row angle: xdot + bias + h-dot ----
        v2f hacc = pk_fma(mk2(s0h, s1h), whq[0], mk2(pt[0] + bq, 0.f));
        hacc = pk_fma(mk2(s2h, s3h), whq[1], hacc);
        hacc = pk_fma(mk2(s4h, s5h), whq[2], hacc);
        hacc = pk_fma(mk2(s6h, s7h), whq[3], hacc);
        float ang = hacc.x + hacc.y;

        // ---- ONE sincos ----
        float sa_own = hw_sin(ang);
        float ca_own = hw_cos(ang);

        // ---- SORTED DPP allgather: absolute wire order, zero DS (verified R15) ----
        float sa_0, sa_1, ca_0, ca_1;
        {
            float p = dpp_xor1(sa_own);
            sa_0 = l0 ? p : sa_own;  sa_1 = l0 ? sa_own : p;
            p = dpp_xor1(ca_own);
            ca_0 = l0 ? p : ca_own;  ca_1 = l0 ? ca_own : p;
        }
        float sa00, sa01, sa10, sa11, ca00, ca01, ca10, ca11;
        {
            float p0 = dpp_xor2(sa_0), p1 = dpp_xor2(sa_1);
            sa00 = l1 ? p0 : sa_0;  sa01 = l1 ? sa_0 : p0;
            sa10 = l1 ? p1 : sa_1;  sa11 = l1 ? sa_1 : p1;
            p0 = dpp_xor2(ca_0); p1 = dpp_xor2(ca_1);
            ca00 = l1 ? p0 : ca_0;  ca01 = l1 ? ca_0 : p0;
            ca10 = l1 ? p1 : ca_1;  ca11 = l1 ? ca_1 : p1;
        }
        float saw[8], caw[8];
        {
            float p;
            p = dpp_xor8(sa00); saw[0] = l3 ? p : sa00; saw[1] = l3 ? sa00 : p;
            p = dpp_xor8(sa01); saw[2] = l3 ? p : sa01; saw[3] = l3 ? sa01 : p;
            p = dpp_xor8(sa10); saw[4] = l3 ? p : sa10; saw[5] = l3 ? sa10 : p;
            p = dpp_xor8(sa11); saw[6] = l3 ? p : sa11; saw[7] = l3 ? sa11 : p;
            p = dpp_xor8(ca00); caw[0] = l3 ? p : ca00; caw[1] = l3 ? ca00 : p;
            p = dpp_xor8(ca01); caw[2] = l3 ? p : ca01; caw[3] = l3 ? ca01 : p;
            p = dpp_xor8(ca10); caw[4] = l3 ? p : ca10; caw[5] = l3 ? ca10 : p;
            p = dpp_xor8(ca11); caw[6] = l3 ? p : ca11; caw[7] = l3 ? ca11 : p;
        }

        // ---- serial transfer chain (verified R9-R16), own-E via sel-fma ----
        float kE = 0.f;
        float d0, d1, zr, zi;
        {
            float AmB = cp0c[0] * caw[0];
            d0 = Chw[0] * (1.f + AmB);
            d1 = -(Chw[0] * (1.f - AmB));
            zr = nSw[0] * (hsp0[0] * caw[0]);
            zi = nSw[0] * (-0.5f * saw[0]);
        }
        #pragma unroll
        for (int w = 1; w < 8; ++w) {
            float gr = hsp0[w] * caw[w];
            float gi = -0.5f * saw[w];
            float AmB = cp0c[w] * caw[w];
            float sum = d0 + d1, dif = d0 - d1;
            float p = gr * zr, qv = gi * zi;
            float Ew = fmaf(4.f, p, sum);
            kE = fmaf(sel[w - 1], Ew, kE);
            float ad = AmB * dif;
            float e1 = sum + ad, e3 = sum - ad;
            float e2 = p - qv, e4 = p + qv;
            float T0 = fmaf(4.f, e2, e1);
            float T1 = fmaf(4.f, e4, e3);
            float f1 = fmaf(gr, sum, zr);
            float f3 = fmaf(AmB, zi, gi * dif);
            d0 = Chw[w] * T0;
            d1 = -(Chw[w] * T1);
            zr = nSw[w] * f1;
            zi = nSw[w] * f3;
        }
        {
            float E7 = (d0 + d1) + 2.f * zr;
            kE = fmaf(sel[7], E7, kE);
        }

        // ---- own activation ----
        float y = hw_exp(kE);
        float a = fmaf(Aa, y, Bb) * hw_rcp(y + 1.f);

        // ---- gather 4 gates (swizzle masks 4,16,20 — verified R13-R16) ----
        float b4 = swz4(a);
        float b16 = swz16(a);
        float b20 = swz20(a);
        bool g1b = (g & 2) != 0;
        bool g0b = (g & 1) != 0;
        float e0 = g1b ? b16 : a;
        float e1s = g1b ? b20 : b4;
        float e2s = g1b ? a : b16;
        float e3s = g1b ? b4 : b20;
        float fv = g0b ? e1s : e0;
        float iv = g0b ? e0 : e1s;
        float gv = g0b ? e3s : e2s;
        float ov = g0b ? e2s : e3s;

        // ---- lane-local LSTM ----
        c_own = fmaf(fv, c_own, iv * gv);
        float e2c = hw_exp(c_own * (2.f * LOG2E));
        hv = ov * ((e2c - 1.f) * hw_rcp(e2c + 1.f));

        if (emit) *optr = hv;
        optr += (size_t)BB * NQ;

        // ---- h allgather butterfly (q^o order; weights pre-folded) ----
        s0h = hv;
        s4h = dpp_xor1(s0h);
        s2h = dpp_xor2(s0h);
        s6h = dpp_xor2(s4h);
        s1h = dpp_xor8(s0h);
        s5h = dpp_xor8(s4h);
        s3h = dpp_xor8(s2h);
        s7h = dpp_xor8(s6h);
    }

    if (emit) {
        hst[b * NQ + q] = hv;
        cst[b * NQ + q] = c_own;
    }
}

extern "C" void kernel_launch(void* const* d_in, const int* in_sizes, int n_in,
                              void* d_out, int out_size, void* d_ws, size_t ws_size,
                              hipStream_t stream) {
    const float* x  = (const float*)d_in[0];
    const float* Wf = (const float*)d_in[1];
    const float* bf = (const float*)d_in[2];
    const float* Pf = (const float*)d_in[3];
    const float* Wi = (const float*)d_in[4];
    const float* bi = (const float*)d_in[5];
    const float* Pi = (const float*)d_in[6];
    const float* Wg = (const float*)d_in[7];
    const float* bg = (const float*)d_in[8];
    const float* Pg = (const float*)d_in[9];
    const float* Wo = (const float*)d_in[10];
    const float* bo = (const float*)d_in[11];
    const float* Po = (const float*)d_in[12];

    float* out = (float*)d_out;
    float* hst = out + (size_t)TS * BB * NQ;
    float* cst = hst + (size_t)BB * NQ;

    qlstm_f<<<BB, 64, 0, stream>>>(x, Wf, bf, Pf, Wi, bi, Pi,
                                   Wg, bg, Pg, Wo, bo, Po,
                                   out, hst, cst);
}